// Round 6
// baseline (1085.959 us; speedup 1.0000x reference)
//
#include <hip/hip_runtime.h>

// 2-layer LSTM, B=2048, T=4096, IN=1, H=8, OUT=1, fp32.
//
// Quad-64 layout: ONE sequence per wave64, lane = L*32 + j*4 + g
//   (L=layer bit5, j=unit bits2-4, g=gate 0..3: i,f,g~,o).
// 2048 waves -> 2 waves/SIMD: two independent recurrence chains per SIMD.
//
// R6: ZERO LDS ops in the steady loop. All cross-lane traffic is VALU:
//   - near-unit h gather (j^1..3): DPP compositions (xor4/8/12)
//   - far-unit h gather (j^4..7): v_permlane16_swap (lane^16) + same DPPs
//   - cross-layer ship (lane^32): v_permlane32_swap + cndmask
// Gate exchange: 4 quad_perm broadcasts; cell computed redundantly x4.
// Pipeline: iter t computes L0(t) and L1(t-2); L0's spare dot ships
// Wih1 . h1 one iteration ahead of consumption; L1's spare dot is the
// projection (Wlin . h2 + blin), stored from lane 32.
// Rows pre-scaled by -log2e (g~ rows -2log2e): act = rcp(1+exp2(z)).

constexpr int Bsz = 2048;
constexpr int Tsz = 4096;

typedef float v2f __attribute__((ext_vector_type(2)));
typedef unsigned int u32;
typedef u32 v2u __attribute__((ext_vector_type(2)));

__device__ __forceinline__ void pk_fma(v2f& acc, v2f a, v2f b) {
    asm("v_pk_fma_f32 %0, %1, %2, %0" : "+v"(acc) : "v"(a), "v"(b));
}

template <int CTRL>
__device__ __forceinline__ float dpp(float v) {
    return __int_as_float(
        __builtin_amdgcn_mov_dpp(__float_as_int(v), CTRL, 0xF, 0xF, true));
}
// quad_perm bcast0..3 = 0x00,0x55,0xAA,0xFF; quad xor3 = 0x1B;
// row_half_mirror (xor7) = 0x141; row_mirror (xor15) = 0x140

// y[lane] = v[lane ^ 16]   (hib4 = lane bit4)
__device__ __forceinline__ float xlane16(float v, bool hib4) {
#if __has_builtin(__builtin_amdgcn_permlane16_swap)
    v2u r = __builtin_amdgcn_permlane16_swap(__float_as_uint(v),
                                             __float_as_uint(v), false, false);
    return __uint_as_float(hib4 ? r.x : r.y);
#else
    u32 a = __float_as_uint(v), b = __float_as_uint(v);
    asm("v_permlane16_swap_b32 %0, %1" : "+v"(a), "+v"(b));
    return __uint_as_float(hib4 ? a : b);
#endif
}

// y[lane] = v[lane ^ 32]   (hib5 = lane bit5)
__device__ __forceinline__ float xlane32(float v, bool hib5) {
#if __has_builtin(__builtin_amdgcn_permlane32_swap)
    v2u r = __builtin_amdgcn_permlane32_swap(__float_as_uint(v),
                                             __float_as_uint(v), false, false);
    return __uint_as_float(hib5 ? r.x : r.y);
#else
    u32 a = __float_as_uint(v), b = __float_as_uint(v);
    asm("v_permlane32_swap_b32 %0, %1" : "+v"(a), "+v"(b));
    return __uint_as_float(hib5 ? a : b);
#endif
}

__global__ void __launch_bounds__(256, 2) lstm2_pl(
    const float* __restrict__ x,      // [B, T]
    const float* __restrict__ Wih0,   // [32, 1]
    const float* __restrict__ Whh0,   // [32, 8]
    const float* __restrict__ bih0,   // [32]
    const float* __restrict__ bhh0,   // [32]
    const float* __restrict__ Wih1,   // [32, 8]
    const float* __restrict__ Whh1,   // [32, 8]
    const float* __restrict__ bih1,   // [32]
    const float* __restrict__ bhh1,   // [32]
    const float* __restrict__ Wlin,   // [1, 8]
    const float* __restrict__ blin,   // [1]
    float* __restrict__ out)          // [B, T]
{
    const int tid  = threadIdx.x;
    const int lane = tid & 63;
    const int g    = lane & 3;
    const int j    = (lane >> 2) & 7;
    const int L    = (lane >> 5) & 1;
    const int seq  = blockIdx.x * 4 + (tid >> 6);   // 1 seq per wave
    const bool hib4 = (lane & 16) != 0;
    const bool hib5 = (lane & 32) != 0;

    const int r = g * 8 + j;          // gate row (PyTorch order i,f,g~,o)

    const float NL2E  = -1.4426950408889634f;   // -log2(e)
    const float N2L2E = -2.8853900817779268f;   // -2*log2(e)
    const bool  isG   = (g == 2);
    const float ws    = isG ? N2L2E : NL2E;
    const float sA    = isG ? 2.0f : 1.0f;      // tanh = 2*sig(2z)-1
    const float oA    = isG ? -1.0f : 0.0f;

    const float* __restrict__ Whh = L ? Whh1 : Whh0;
    const float* __restrict__ bih = L ? bih1 : bih0;
    const float* __restrict__ bhh = L ? bhh1 : bhh0;

    // wp1: own hh row; wp2: spare dot (L0: Wih1 row for partner L1 lane,
    // L1: Wlin projection). Slot q pairs k = j^(2q), j^(2q+1).
    v2f wp1[4], wp2[4];
#pragma unroll
    for (int q = 0; q < 4; ++q) {
        const int kx = j ^ (2 * q);
        const int ky = j ^ (2 * q + 1);
        wp1[q] = v2f{Whh[r * 8 + kx] * ws, Whh[r * 8 + ky] * ws};
        wp2[q] = L ? v2f{Wlin[kx], Wlin[ky]}
                   : v2f{Wih1[r * 8 + kx] * ws, Wih1[r * 8 + ky] * ws};
    }
    const float bias = (bih[r] + bhh[r]) * ws;
    const float wx   = L ? 0.0f : Wih0[r] * ws;
    const float b2   = L ? blin[0] : 0.0f;
    const float mL   = L ? 1.0f : 0.0f;   // consume shipped dot only on L1
    const float keep = 1.0f - mL;

    const float* __restrict__ xp = x + (size_t)seq * Tsz;
    float* __restrict__ op       = out + (size_t)seq * Tsz;
    const bool storeLane = (lane == 32);  // L1, j=0, g=0

    v2f hp[4];
#pragma unroll
    for (int q = 0; q < 4; ++q) hp[q] = v2f{0.0f, 0.0f};
    float c = 0.0f, h = 0.0f, recv = 0.0f;

    float xn1 = xp[0];
    float xn2 = xp[1];

    auto body = [&](int t) {
        const float xt = xn1;
        xn1 = xn2;
        int ti = t + 2; ti = (ti < Tsz) ? ti : (Tsz - 1);
        xn2 = xp[ti];

        // dots over hp (own-layer h from prev iter's gather)
        v2f a1 = v2f{fmaf(wx, xt, bias), 0.0f};
        v2f a2 = v2f{b2, 0.0f};
#pragma unroll
        for (int q = 0; q < 4; ++q) {
            pk_fma(a1, wp1[q], hp[q]);
            pk_fma(a2, wp2[q], hp[q]);
        }
        const float d1 = a1.x + a1.y;
        const float d2 = a2.x + a2.y;

        // projection store: L1 lane32's d2 = blin + Wlin . h2(t-3)
        if (t >= 3 && storeLane) op[t - 3] = d2;

        // consume last iter's cross-layer dot, ship this iter's (VALU xor32)
        const float rOld = recv;
        recv = xlane32(d2, hib5);     // L1 receives L0's Wih1 . h1

        const float z = fmaf(mL, rOld, d1);
        // gate activation (row pre-scaled): sig or tanh via fma
        float a = fmaf(sA,
                       __builtin_amdgcn_rcpf(1.0f + __builtin_amdgcn_exp2f(z)),
                       oA);
        // quad broadcast: all 4 gates of unit j to every lane of the quad
        const float gi = dpp<0x00>(a);
        const float gf = dpp<0x55>(a);
        const float gG = dpp<0xAA>(a);
        const float go = dpp<0xFF>(a);
        c = fmaf(gf, c, gi * gG);
        const float e  = __builtin_amdgcn_exp2f(c * N2L2E);
        const float th = fmaf(2.0f, __builtin_amdgcn_rcpf(1.0f + e), -1.0f);
        h = go * th;   // every lane of quad j holds h[j] (redundant x4)

        // h all-gather within the 32-lane layer half (all VALU)
        const float m7  = dpp<0x141>(h);     // ^7
        const float h1_ = dpp<0x1B>(m7);     // ^7^3  = ^4  -> j^1
        const float m15 = dpp<0x140>(h);     // ^15
        const float h2_ = dpp<0x141>(m15);   // ^15^7 = ^8  -> j^2
        const float h3_ = dpp<0x1B>(m15);    // ^15^3 = ^12 -> j^3
        const float hs  = xlane16(h, hib4);  // ^16 -> j^4
        const float m7s = dpp<0x141>(hs);    // ^16^7
        const float h5_ = dpp<0x1B>(m7s);    // ^16^4 = ^20 -> j^5
        const float m15s= dpp<0x140>(hs);    // ^16^15
        const float h6_ = dpp<0x141>(m15s);  // ^16^8 = ^24 -> j^6
        const float h7_ = dpp<0x1B>(m15s);   // ^16^12= ^28 -> j^7
        hp[0] = v2f{h,   h1_};
        hp[1] = v2f{h2_, h3_};
        hp[2] = v2f{hs,  h5_};
        hp[3] = v2f{h6_, h7_};
    };

    // pipeline fill: L1 state must be zero entering the steady loop
    body(0);
    h *= keep; c *= keep;
#pragma unroll
    for (int q = 0; q < 4; ++q) { hp[q].x *= keep; hp[q].y *= keep; }
    body(1);
    h *= keep; c *= keep;
#pragma unroll
    for (int q = 0; q < 4; ++q) { hp[q].x *= keep; hp[q].y *= keep; }

    // steady: iter t computes L0(t), L1(t-2), stores out[t-3]
    for (int t = 2; t <= Tsz + 2; ++t) body(t);
}

extern "C" void kernel_launch(void* const* d_in, const int* in_sizes, int n_in,
                              void* d_out, int out_size, void* d_ws, size_t ws_size,
                              hipStream_t stream) {
    const float* x    = (const float*)d_in[0];
    const float* Wih0 = (const float*)d_in[1];
    const float* Whh0 = (const float*)d_in[2];
    const float* bih0 = (const float*)d_in[3];
    const float* bhh0 = (const float*)d_in[4];
    const float* Wih1 = (const float*)d_in[5];
    const float* Whh1 = (const float*)d_in[6];
    const float* bih1 = (const float*)d_in[7];
    const float* bhh1 = (const float*)d_in[8];
    const float* Wlin = (const float*)d_in[9];
    const float* blin = (const float*)d_in[10];
    float* out = (float*)d_out;

    dim3 grid(Bsz / 4);   // 4 waves/block, 1 seq/wave -> 512 blocks, 2048 waves
    dim3 block(256);
    hipLaunchKernelGGL(lstm2_pl, grid, block, 0, stream,
                       x, Wih0, Whh0, bih0, bhh0,
                       Wih1, Whh1, bih1, bhh1, Wlin, blin, out);
}

// Round 8
// 896.878 us; speedup vs baseline: 1.2108x; 1.2108x over previous
//
#include <hip/hip_runtime.h>

// 2-layer LSTM, B=2048, T=4096, IN=1, H=8, OUT=1, fp32.
//
// R8 = R7 (mirror-partial far dots + scalar fmac + unroll4) with CORRECTED
// pipeline bookkeeping.
// Layout: 1 seq/wave64, lane = L*32 + j*4 + g (g=gate i,f,g~,o; j=unit;
// L=layer). 2048 waves = 2 waves/SIMD.
//
// Near h (units j..j^3) via 5 intra-row DPPs. Far-half dot: each lane
// computes the far partial OF ITS MIRROR LANE's row (weights
// W[row(lane^16)][j^i]) from its near h, ships via one ds_swizzle xor16.
// Cross-layer: d2 ships via ds_bpermute lane^32 and is consumed TWO
// iterations later: recvB(m) = d2(m-2) = Wih1 . h1(m-3)  =>  L1 runs
// THREE iters behind L0 (h2(s) computed at iter s+3). Projection dot at
// iter m uses h2(m-4) -> store op[m-4]; fills = iters 0,1,2; first L1
// step at iter 3; steady m = 4..Tsz+3.
// Gates pre-scaled by -log2e (g~ rows -2log2e): act = rcp(1+exp2(z)).

constexpr int Bsz = 2048;
constexpr int Tsz = 4096;

template <int CTRL>
__device__ __forceinline__ float dpp(float v) {
    return __int_as_float(
        __builtin_amdgcn_mov_dpp(__float_as_int(v), CTRL, 0xF, 0xF, true));
}
// quad_perm bcast0..3 = 0x00,0x55,0xAA,0xFF; quad xor3 = 0x1B;
// row_half_mirror (xor7) = 0x141; row_mirror (xor15) = 0x140

__device__ __forceinline__ float swz16(float v) {
    // ds_swizzle bit mode, xor 0x10 within each 32-lane group
    return __int_as_float(
        __builtin_amdgcn_ds_swizzle(__float_as_int(v), (16 << 10) | 0x1f));
}

__device__ __forceinline__ float bperm(int addr, float v) {
    return __int_as_float(__builtin_amdgcn_ds_bpermute(addr, __float_as_int(v)));
}

__global__ void __launch_bounds__(256, 2) lstm2_mp2(
    const float* __restrict__ x,      // [B, T]
    const float* __restrict__ Wih0,   // [32, 1]
    const float* __restrict__ Whh0,   // [32, 8]
    const float* __restrict__ bih0,   // [32]
    const float* __restrict__ bhh0,   // [32]
    const float* __restrict__ Wih1,   // [32, 8]
    const float* __restrict__ Whh1,   // [32, 8]
    const float* __restrict__ bih1,   // [32]
    const float* __restrict__ bhh1,   // [32]
    const float* __restrict__ Wlin,   // [1, 8]
    const float* __restrict__ blin,   // [1]
    float* __restrict__ out)          // [B, T]
{
    const int tid  = threadIdx.x;
    const int lane = tid & 63;
    const int g    = lane & 3;
    const int j    = (lane >> 2) & 7;
    const int L    = (lane >> 5) & 1;
    const int seq  = blockIdx.x * 4 + (tid >> 6);

    const int jm = j ^ 4;             // mirror lane's unit
    const int r  = g * 8 + j;         // own gate row
    const int rm = g * 8 + jm;        // mirror lane's gate row

    const float NL2E  = -1.4426950408889634f;
    const float N2L2E = -2.8853900817779268f;
    const bool  isG   = (g == 2);
    const float ws    = isG ? N2L2E : NL2E;
    const float sA    = isG ? 2.0f : 1.0f;      // tanh = 2*sig(2z)-1
    const float oA    = isG ? -1.0f : 0.0f;

    const float* __restrict__ Whh = L ? Whh1 : Whh0;
    const float* __restrict__ bih = L ? bih1 : bih0;
    const float* __restrict__ bhh = L ? bhh1 : bhh0;

    // near weights (own row) + mirror-row weights, k = j^i for i=0..3
    float wn1[4], wm1[4], wn2[4], wm2[4];
#pragma unroll
    for (int i = 0; i < 4; ++i) {
        const int k = j ^ i;
        wn1[i] = Whh[r * 8 + k] * ws;
        wm1[i] = Whh[rm * 8 + k] * ws;
        wn2[i] = L ? Wlin[k] : Wih1[r * 8 + k] * ws;
        wm2[i] = L ? Wlin[k] : Wih1[rm * 8 + k] * ws;
    }
    const float bias = (bih[r] + bhh[r]) * ws;
    const float wx   = L ? 0.0f : Wih0[r] * ws;
    const float b2   = L ? blin[0] : 0.0f;
    const float mL   = L ? 1.0f : 0.0f;
    const float keep = 1.0f - mL;
    const int  xaddr = (lane ^ 32) * 4;   // bpermute: cross layer halves

    const float* __restrict__ xp = x + (size_t)seq * Tsz;
    float* __restrict__ op       = out + (size_t)seq * Tsz;
    const bool storeLane = (lane == 32);

    float hn0 = 0.0f, hn1 = 0.0f, hn2 = 0.0f, hn3 = 0.0f;
    float c = 0.0f, h = 0.0f;
    float recvA = 0.0f, recvB = 0.0f;

    auto body = [&](float xt, bool fill, float* storePtr) {
        // -- mirror partials from entering hn (= h(m-1)); ship early
        float am1 = wm1[0] * hn0;
        am1 = fmaf(wm1[1], hn1, am1);
        am1 = fmaf(wm1[2], hn2, am1);
        am1 = fmaf(wm1[3], hn3, am1);
        float am2 = wm2[0] * hn0;
        am2 = fmaf(wm2[1], hn1, am2);
        am2 = fmaf(wm2[2], hn2, am2);
        am2 = fmaf(wm2[3], hn3, am2);
        const float s1 = swz16(am1);   // far half of OWN row's hh-dot
        const float s2 = swz16(am2);   // far half of OWN row's spare dot

        // -- near dots
        float an1 = fmaf(wx, xt, bias);
        an1 = fmaf(wn1[0], hn0, an1);
        an1 = fmaf(wn1[1], hn1, an1);
        an1 = fmaf(wn1[2], hn2, an1);
        an1 = fmaf(wn1[3], hn3, an1);
        float an2 = fmaf(wn2[0], hn0, b2);
        an2 = fmaf(wn2[1], hn1, an2);
        an2 = fmaf(wn2[2], hn2, an2);
        an2 = fmaf(wn2[3], hn3, an2);

        // -- z: near + far(ship) + cross-layer dot from 2 iters ago
        const float z = fmaf(mL, recvB, an1 + s1);

        // -- activation (pre-scaled): sig or tanh
        float a = fmaf(sA,
                       __builtin_amdgcn_rcpf(1.0f + __builtin_amdgcn_exp2f(z)),
                       oA);
        const float gi = dpp<0x00>(a);
        const float gf = dpp<0x55>(a);
        const float gG = dpp<0xAA>(a);
        const float go = dpp<0xFF>(a);
        c = fmaf(gf, c, gi * gG);
        const float e  = __builtin_amdgcn_exp2f(c * N2L2E);
        const float th = fmaf(2.0f, __builtin_amdgcn_rcpf(1.0f + e), -1.0f);
        h = go * th;

        if (fill) { h *= keep; c *= keep; }   // keep L1 state at zero

        // -- near-h gather for next iter (intra-row DPP only)
        const float m7  = dpp<0x141>(h);     // ^7
        const float m15 = dpp<0x140>(h);     // ^15
        hn0 = h;                             // j
        hn1 = dpp<0x1B>(m7);                 // ^7^3  = ^4  -> j^1
        hn2 = dpp<0x141>(m15);               // ^15^7 = ^8  -> j^2
        hn3 = dpp<0x1B>(m15);                // ^15^3 = ^12 -> j^3

        // -- tail: full spare dot (uses h(m-1) values), store, ship
        const float d2 = an2 + s2;           // L0: Wih1.h1(m-1); L1: proj(h2(m-4))
        if (storePtr && storeLane) *storePtr = d2;
        recvB = recvA;                       // recvB for iter m+1 = d2(m-1)
        recvA = bperm(xaddr, d2);            // d2(m)
    };

    // ---- fills: iters 0,1,2 keep L1 state zero; iter 3 = L1 step 0
    body(xp[0], true, nullptr);
    body(xp[1], true, nullptr);
    body(xp[2], true, nullptr);
    body(xp[3], false, nullptr);             // computes h2(0); proj invalid

    // ---- steady, unrolled x4: m = 4 .. Tsz+3, store op[m-4]
    float xc[4];
#pragma unroll
    for (int u = 0; u < 4; ++u) xc[u] = xp[4 + u];   // x(4..7), Tsz >> 8
    for (int ck = 0; ck < Tsz / 4; ++ck) {
        const int base = 4 + 4 * ck;
        float xf[4];
#pragma unroll
        for (int u = 0; u < 4; ++u) {
            int idx = base + 4 + u;
            idx = (idx < Tsz) ? idx : (Tsz - 1);
            xf[u] = xp[idx];                 // prefetch next chunk
        }
#pragma unroll
        for (int u = 0; u < 4; ++u)
            body(xc[u], false, op + (4 * ck + u));   // op[m-4]
#pragma unroll
        for (int u = 0; u < 4; ++u) xc[u] = xf[u];
    }
}

extern "C" void kernel_launch(void* const* d_in, const int* in_sizes, int n_in,
                              void* d_out, int out_size, void* d_ws, size_t ws_size,
                              hipStream_t stream) {
    const float* x    = (const float*)d_in[0];
    const float* Wih0 = (const float*)d_in[1];
    const float* Whh0 = (const float*)d_in[2];
    const float* bih0 = (const float*)d_in[3];
    const float* bhh0 = (const float*)d_in[4];
    const float* Wih1 = (const float*)d_in[5];
    const float* Whh1 = (const float*)d_in[6];
    const float* bih1 = (const float*)d_in[7];
    const float* bhh1 = (const float*)d_in[8];
    const float* Wlin = (const float*)d_in[9];
    const float* blin = (const float*)d_in[10];
    float* out = (float*)d_out;

    dim3 grid(Bsz / 4);   // 4 waves/block, 1 seq/wave -> 512 blocks, 2048 waves
    dim3 block(256);
    hipLaunchKernelGGL(lstm2_mp2, grid, block, 0, stream,
                       x, Wih0, Whh0, bih0, bhh0,
                       Wih1, Whh1, bih1, bhh1, Wlin, blin, out);
}